// Round 7
// baseline (131.460 us; speedup 1.0000x reference)
//
#include <hip/hip_runtime.h>
#include <math.h>

#define DIM 64
#define HEADS 4
#define BB 8
#define QQ 128
#define VV 128
#define NN (BB*QQ)   // 1024

typedef float f2 __attribute__((ext_vector_type(2)));

// DPP quad_perm(1,0,3,2): swap adjacent lanes (xor 1). VALU, no DS.
__device__ __forceinline__ float dpp_swap1(float x) {
    return __int_as_float(__builtin_amdgcn_update_dpp(
        0, __float_as_int(x), 0xB1, 0xF, 0xF, true));
}
// wave_shr:1 — lane j gets lane j-1 (lane 0 -> 0 via bound_ctrl). VALU, no DS.
__device__ __forceinline__ float dpp_wshr1(float x) {
    return __int_as_float(__builtin_amdgcn_update_dpp(
        0, __float_as_int(x), 0x138, 0xF, 0xF, true));
}
// wave_shl:1 — lane j gets lane j+1 (lane 63 -> 0 via bound_ctrl). VALU, no DS.
__device__ __forceinline__ float dpp_wshl1(float x) {
    return __int_as_float(__builtin_amdgcn_update_dpp(
        0, __float_as_int(x), 0x130, 0xF, 0xF, true));
}

// K1: Av[h][row][j] = (re,im) of sum_i values[row,i] * U[h, 64+i, j]
__global__ __launch_bounds__(256) void k_av(const float* __restrict__ values,
                                            const float* __restrict__ U_re,
                                            const float* __restrict__ U_im,
                                            f2* __restrict__ Av) {
    int tid = blockIdx.x * blockDim.x + threadIdx.x;
    int w = tid >> 6;            // 0..1023
    int j = tid & 63;
    int h = w >> 8;              // 0..3
    int r0 = (w & 255) << 2;     // first of 4 rows within head h (0..1020)
    const float* vrow = values + r0 * DIM;                     // wave-uniform
    const float* ur = U_re + (h * 2 * DIM + DIM) * DIM + j;    // bottom half
    const float* ui = U_im + (h * 2 * DIM + DIM) * DIM + j;
    f2 a0 = 0.f, a1 = 0.f, a2 = 0.f, a3 = 0.f;
    #pragma unroll 8
    for (int i = 0; i < DIM; ++i) {
        f2 u; u.x = ur[i * DIM]; u.y = ui[i * DIM];
        a0 += vrow[i] * u;                 // s_load scalars broadcast
        a1 += vrow[DIM + i] * u;
        a2 += vrow[2 * DIM + i] * u;
        a3 += vrow[3 * DIM + i] * u;
    }
    f2* out = Av + (h * 1024 + r0) * DIM + j;
    out[0] = a0; out[DIM] = a1; out[2 * DIM] = a2; out[3 * DIM] = a3;
}

// K2: block = row n (1024 blocks -> 4 blocks/CU, 16 waves/CU). 4 waves = 4
// heads, each wave scans ONE row unpacked (scalar complex state, lane = dim).
// More waves/SIMD to cover the serial chain latency. No DS / branches in scan.
__global__ __launch_bounds__(256, 4) void k_rnn_dense(
        const float* __restrict__ queries,
        const float* __restrict__ U_re,
        const float* __restrict__ U_im,
        const float* __restrict__ bias,
        const float* __restrict__ theta1,
        const float* __restrict__ phi1,
        const float* __restrict__ theta2,
        const float* __restrict__ phi2,
        const float* __restrict__ omega,
        const f2* __restrict__ Av,
        const float* __restrict__ W_dense,
        const float* __restrict__ b_dense,
        float* __restrict__ y) {
    int n = blockIdx.x;        // 0..1023 (row)
    int t = threadIdx.x;
    int h = t >> 6;            // head = wave
    int j = t & 63;            // state dim = lane
    int b = n >> 7;

    // ---- layer-1 coefficients: out = A1*self + B1*partner(xor 1) ----
    int k1 = j >> 1;
    float th1 = theta1[h * 32 + k1], ph1 = phi1[h * 32 + k1];
    float c1 = cosf(th1), s1 = sinf(th1);
    float A1r, A1i, B1r, B1i;
    if ((j & 1) == 0) {        // 'a': e1*(c1*a - s1*b)
        float er = cosf(ph1), ei = sinf(ph1);
        A1r = er * c1; A1i = ei * c1;
        B1r = -er * s1; B1i = -ei * s1;
    } else {                   // 'b': s1*a + c1*b
        A1r = c1; A1i = 0.f;
        B1r = s1; B1i = 0.f;
    }

    // ---- layer-2 (+omega): s = A2*t + BL*t[j+1] + BR*t[j-1], parity-folded ----
    float A2r, A2i, BLr, BLi, BRr, BRi;
    if (j == 0 || j == 63) {
        A2r = 1.f; A2i = 0.f; BLr = 0.f; BLi = 0.f; BRr = 0.f; BRi = 0.f;
    } else {
        int k2 = (j - 1) >> 1;
        float th2 = theta2[h * 31 + k2], ph2 = phi2[h * 31 + k2];
        float c2 = cosf(th2), s2 = sinf(th2);
        if (j & 1) {           // odd = 'a': e2*(c2*self - s2*next)
            float er = cosf(ph2), ei = sinf(ph2);
            A2r = er * c2; A2i = ei * c2;
            BLr = -er * s2; BLi = -ei * s2;
            BRr = 0.f; BRi = 0.f;
        } else {               // even = 'b': s2*prev + c2*self
            A2r = c2; A2i = 0.f;
            BRr = s2; BRi = 0.f;
            BLr = 0.f; BLi = 0.f;
        }
    }
    {   // fold exp(i*omega) into A2, BL, BR
        float om = omega[h * 64 + j];
        float eor = cosf(om), eoi = sinf(om);
        float tr, ti;
        tr = A2r * eor - A2i * eoi; ti = A2r * eoi + A2i * eor; A2r = tr; A2i = ti;
        tr = BLr * eor - BLi * eoi; ti = BLr * eoi + BLi * eor; BLr = tr; BLi = ti;
        tr = BRr * eor - BRi * eoi; ti = BRr * eoi + BRi * eor; BRr = tr; BRi = ti;
    }
    float bj = bias[h * 64 + j];

    // ---- Aq: uq = q_row . U_top[h]; query row block-uniform -> s_load ----
    const float* qrow = queries + n * DIM;
    const float* ur = U_re + (h * 2 * DIM) * DIM + j;
    const float* ui = U_im + (h * 2 * DIM) * DIM + j;
    float uqr = 0.f, uqi = 0.f;
    #pragma unroll 8
    for (int i = 0; i < DIM; ++i) {
        float a = qrow[i];
        uqr = fmaf(a, ur[i * DIM], uqr);
        uqi = fmaf(a, ui[i * DIM], uqi);
    }

    const f2* Avp = Av + (h * 1024 + b * 128) * DIM + j;

    float hr = 0.f, hi = 0.f;
    f2 av0 = Avp[0];
    float uvr = uqr + av0.x, uvi = uqi + av0.y;   // step-0 input, off-chain
    f2 avn = Avp[DIM];                            // step-1 Av, in flight
    #pragma unroll 4
    for (int v = 0; v < VV; ++v) {
        f2 av2 = Avp[((v + 2) & 127) * DIM];      // distance-2 prefetch
        // layer 1
        float pr = dpp_swap1(hr), pi = dpp_swap1(hi);
        float t_r = (A1r * hr - A1i * hi) + (B1r * pr - B1i * pi);
        float t_i = (A1r * hi + A1i * hr) + (B1r * pi + B1i * pr);
        // layer 2 (+omega)
        float Lr = dpp_wshl1(t_r), Li = dpp_wshl1(t_i);
        float Rr = dpp_wshr1(t_r), Ri = dpp_wshr1(t_i);
        float s_r = (A2r * t_r - A2i * t_i) + (BLr * Lr - BLi * Li) + (BRr * Rr - BRi * Ri);
        float s_i = (A2r * t_i + A2i * t_r) + (BLr * Li + BLi * Lr) + (BRr * Ri + BRi * Rr);
        // input (precomputed off-chain)
        float zr = s_r + uvr;
        float zi = s_i + uvi;
        // next step's input term — depends only on in-flight load
        uvr = uqr + avn.x; uvi = uqi + avn.y;
        avn = av2;
        // modrelu: m = sqrt(q2), 1/m == rs; sc = relu(m + b) * rs
        float q2 = fmaf(zr, zr, fmaf(zi, zi, 1e-10f));
        float rs = __builtin_amdgcn_rsqf(q2);
        float tp = fmaxf(fmaf(q2, rs, bj), 0.f);
        float sc = tp * rs;
        hr = zr * sc; hi = zi * sc;
    }

    // ---- fused dense for row n ----
    __shared__ float s_acc[HEADS * DIM];   // 256
    __shared__ float s_part[256];
    s_acc[h * 64 + j] = hr;                // Re(hT)
    __syncthreads();

    {   // thread t: k-quarter qq = t>>6, col jj = t&63
        int qq = t >> 6, jj = t & 63;
        const float* Wp = W_dense + (qq * 64) * DIM + jj;
        const float* ap = &s_acc[qq * 64];
        float part = 0.f;
        #pragma unroll 8
        for (int k = 0; k < 64; ++k)
            part = fmaf(ap[k], Wp[k * DIM], part);   // ap broadcast, Wp coalesced
        s_part[t] = part;
    }
    __syncthreads();
    if (t < 64) {
        y[n * DIM + t] = b_dense[t] + s_part[t] + s_part[64 + t]
                       + s_part[128 + t] + s_part[192 + t];
    }
}

extern "C" void kernel_launch(void* const* d_in, const int* in_sizes, int n_in,
                              void* d_out, int out_size, void* d_ws, size_t ws_size,
                              hipStream_t stream) {
    const float* queries = (const float*)d_in[0];
    const float* values  = (const float*)d_in[1];
    const float* U_re    = (const float*)d_in[2];
    const float* U_im    = (const float*)d_in[3];
    const float* bias    = (const float*)d_in[4];
    const float* theta1  = (const float*)d_in[5];
    const float* phi1    = (const float*)d_in[6];
    const float* theta2  = (const float*)d_in[7];
    const float* phi2    = (const float*)d_in[8];
    const float* omega   = (const float*)d_in[9];
    const float* W_dense = (const float*)d_in[10];
    const float* b_dense = (const float*)d_in[11];
    float* y = (float*)d_out;

    f2* Av = (f2*)d_ws;   // HEADS*1024*64 f2 = 2 MB

    k_av<<<256, 256, 0, stream>>>(values, U_re, U_im, Av);
    k_rnn_dense<<<1024, 256, 0, stream>>>(queries, U_re, U_im, bias, theta1,
                                          phi1, theta2, phi2, omega, Av,
                                          W_dense, b_dense, y);
}

// Round 8
// 119.487 us; speedup vs baseline: 1.1002x; 1.1002x over previous
//
#include <hip/hip_runtime.h>
#include <math.h>

#define DIM 64
#define HEADS 4
#define BB 8
#define QQ 128
#define VV 128
#define NN (BB*QQ)   // 1024

typedef float f2 __attribute__((ext_vector_type(2)));

// DPP quad_perm(1,0,3,2): swap adjacent lanes (xor 1). VALU, no DS.
__device__ __forceinline__ float dpp_swap1(float x) {
    return __int_as_float(__builtin_amdgcn_update_dpp(
        0, __float_as_int(x), 0xB1, 0xF, 0xF, true));
}
// wave_shr:1 — lane j gets lane j-1 (lane 0 -> 0 via bound_ctrl). VALU, no DS.
__device__ __forceinline__ float dpp_wshr1(float x) {
    return __int_as_float(__builtin_amdgcn_update_dpp(
        0, __float_as_int(x), 0x138, 0xF, 0xF, true));
}
// wave_shl:1 — lane j gets lane j+1 (lane 63 -> 0 via bound_ctrl). VALU, no DS.
__device__ __forceinline__ float dpp_wshl1(float x) {
    return __int_as_float(__builtin_amdgcn_update_dpp(
        0, __float_as_int(x), 0x130, 0xF, 0xF, true));
}
__device__ __forceinline__ f2 dpp2_swap1(f2 x) {
    f2 r; r.x = dpp_swap1(x.x); r.y = dpp_swap1(x.y); return r;
}
__device__ __forceinline__ f2 dpp2_shl1(f2 x) {
    f2 r; r.x = dpp_wshl1(x.x); r.y = dpp_wshl1(x.y); return r;
}
__device__ __forceinline__ f2 dpp2_shr1(f2 x) {
    f2 r; r.x = dpp_wshr1(x.x); r.y = dpp_wshr1(x.y); return r;
}

// K1: Av[h][row][j] = (re,im) of sum_i values[row,i] * U[h, 64+i, j]
__global__ __launch_bounds__(256) void k_av(const float* __restrict__ values,
                                            const float* __restrict__ U_re,
                                            const float* __restrict__ U_im,
                                            f2* __restrict__ Av) {
    int tid = blockIdx.x * blockDim.x + threadIdx.x;
    int w = tid >> 6;            // 0..1023
    int j = tid & 63;
    int h = w >> 8;              // 0..3
    int r0 = (w & 255) << 2;     // first of 4 rows within head h (0..1020)
    const float* vrow = values + r0 * DIM;                     // wave-uniform
    const float* ur = U_re + (h * 2 * DIM + DIM) * DIM + j;    // bottom half
    const float* ui = U_im + (h * 2 * DIM + DIM) * DIM + j;
    f2 a0 = 0.f, a1 = 0.f, a2 = 0.f, a3 = 0.f;
    #pragma unroll 8
    for (int i = 0; i < DIM; ++i) {
        f2 u; u.x = ur[i * DIM]; u.y = ui[i * DIM];
        a0 += vrow[i] * u;                 // s_load scalars broadcast
        a1 += vrow[DIM + i] * u;
        a2 += vrow[2 * DIM + i] * u;
        a3 += vrow[3 * DIM + i] * u;
    }
    f2* out = Av + (h * 1024 + r0) * DIM + j;
    out[0] = a0; out[DIM] = a1; out[2 * DIM] = a2; out[3 * DIM] = a3;
}

// K2: block = (b, q): 4 waves = 4 heads; each wave scans TWO rows (q, q+64),
// states packed as f2 (component = row). No DS / branches in the scan.
// Av loads kept 4 steps ahead (rotating register pipeline) to cover L3
// latency (cross-XCD reads of Av don't hit the local L2).
__global__ __launch_bounds__(256) void k_rnn_dense(
        const float* __restrict__ queries,
        const float* __restrict__ U_re,
        const float* __restrict__ U_im,
        const float* __restrict__ bias,
        const float* __restrict__ theta1,
        const float* __restrict__ phi1,
        const float* __restrict__ theta2,
        const float* __restrict__ phi2,
        const float* __restrict__ omega,
        const f2* __restrict__ Av,
        const float* __restrict__ W_dense,
        const float* __restrict__ b_dense,
        float* __restrict__ y) {
    int b = blockIdx.x >> 6;   // 0..7
    int q = blockIdx.x & 63;   // 0..63
    int t = threadIdx.x;
    int h = t >> 6;            // head = wave
    int j = t & 63;            // state dim = lane
    int n0 = b * 128 + q;      // row A (block-uniform)
    int n1 = n0 + 64;          // row B

    // ---- layer-1 coefficients: out = A1*self + B1*partner(xor 1) ----
    int k1 = j >> 1;
    float th1 = theta1[h * 32 + k1], ph1 = phi1[h * 32 + k1];
    float c1 = cosf(th1), s1 = sinf(th1);
    float A1r, A1i, B1r, B1i;
    if ((j & 1) == 0) {        // 'a': e1*(c1*a - s1*b)
        float er = cosf(ph1), ei = sinf(ph1);
        A1r = er * c1; A1i = ei * c1;
        B1r = -er * s1; B1i = -ei * s1;
    } else {                   // 'b': s1*a + c1*b
        A1r = c1; A1i = 0.f;
        B1r = s1; B1i = 0.f;
    }

    // ---- layer-2 (+omega): s = A2*t + BL*t[j+1] + BR*t[j-1], parity-folded ----
    float A2r, A2i, BLr, BLi, BRr, BRi;
    if (j == 0 || j == 63) {
        A2r = 1.f; A2i = 0.f; BLr = 0.f; BLi = 0.f; BRr = 0.f; BRi = 0.f;
    } else {
        int k2 = (j - 1) >> 1;
        float th2 = theta2[h * 31 + k2], ph2 = phi2[h * 31 + k2];
        float c2 = cosf(th2), s2 = sinf(th2);
        if (j & 1) {           // odd = 'a': e2*(c2*self - s2*next)
            float er = cosf(ph2), ei = sinf(ph2);
            A2r = er * c2; A2i = ei * c2;
            BLr = -er * s2; BLi = -ei * s2;
            BRr = 0.f; BRi = 0.f;
        } else {               // even = 'b': s2*prev + c2*self
            A2r = c2; A2i = 0.f;
            BRr = s2; BRi = 0.f;
            BLr = 0.f; BLi = 0.f;
        }
    }
    {   // fold exp(i*omega) into A2, BL, BR
        float om = omega[h * 64 + j];
        float eor = cosf(om), eoi = sinf(om);
        float tr, ti;
        tr = A2r * eor - A2i * eoi; ti = A2r * eoi + A2i * eor; A2r = tr; A2i = ti;
        tr = BLr * eor - BLi * eoi; ti = BLr * eoi + BLi * eor; BLr = tr; BLi = ti;
        tr = BRr * eor - BRi * eoi; ti = BRr * eoi + BRi * eor; BRr = tr; BRi = ti;
    }
    float bj = bias[h * 64 + j];

    // ---- Aq for both rows (packed); query rows block-uniform -> s_load ----
    const float* qrow0 = queries + n0 * DIM;
    const float* qrow1 = queries + n1 * DIM;
    const float* ur = U_re + (h * 2 * DIM) * DIM + j;
    const float* ui = U_im + (h * 2 * DIM) * DIM + j;
    f2 Uqr = 0.f, Uqi = 0.f;   // component 0 = row n0, 1 = row n1
    #pragma unroll 8
    for (int i = 0; i < DIM; ++i) {
        f2 a; a.x = qrow0[i]; a.y = qrow1[i];
        float wr = ur[i * DIM], wi = ui[i * DIM];
        Uqr += a * wr;
        Uqi += a * wi;
    }

    const f2* p = Av + (h * 1024 + b * 128) * DIM + j;

    // 4-deep Av pipeline: a0..a3 hold Av[v .. v+3]; each iter loads Av[v+4].
    // The tail over-reads 4 rows (2 KB) of dead d_ws data — never used.
    f2 a0 = p[0], a1 = p[DIM], a2 = p[2 * DIM], a3 = p[3 * DIM];
    f2 Hr = 0.f, Hi = 0.f;
    f2 uvr = Uqr + a0.x, uvi = Uqi + a0.y;   // input term for step 0, off-chain
    #pragma unroll 4
    for (int v = 0; v < VV; ++v) {
        f2 a4 = p[4 * DIM];                  // offset:2048, 4 steps ahead
        p += DIM;
        // layer 1
        f2 Pr = dpp2_swap1(Hr), Pi = dpp2_swap1(Hi);
        f2 Tr = (A1r * Hr - A1i * Hi) + (B1r * Pr - B1i * Pi);
        f2 Ti = (A1r * Hi + A1i * Hr) + (B1r * Pi + B1i * Pr);
        // layer 2 (+omega)
        f2 Lr = dpp2_shl1(Tr), Li = dpp2_shl1(Ti);
        f2 Rr = dpp2_shr1(Tr), Ri = dpp2_shr1(Ti);
        f2 Sr = (A2r * Tr - A2i * Ti) + (BLr * Lr - BLi * Li) + (BRr * Rr - BRi * Ri);
        f2 Si = (A2r * Ti + A2i * Tr) + (BLr * Li + BLi * Lr) + (BRr * Ri + BRi * Rr);
        // input (precomputed off-chain)
        f2 Zr = Sr + uvr;
        f2 Zi = Si + uvi;
        // next step's input term — from the pipeline, far off-chain
        uvr = Uqr + a1.x; uvi = Uqi + a1.y;
        a0 = a1; a1 = a2; a2 = a3; a3 = a4;  // rotate (free under unroll)
        // modrelu: sc = relu(m+b)/m = max(1 + b/m, 0), 1/m = rsq(|z|^2+eps)
        f2 q2 = Zr * Zr + Zi * Zi + 1e-10f;
        f2 rs; rs.x = __builtin_amdgcn_rsqf(q2.x); rs.y = __builtin_amdgcn_rsqf(q2.y);
        f2 sc;
        sc.x = fmaxf(fmaf(bj, rs.x, 1.f), 0.f);
        sc.y = fmaxf(fmaf(bj, rs.y, 1.f), 0.f);
        Hr = Zr * sc; Hi = Zi * sc;
    }

    // ---- fused dense for rows n0, n1 ----
    __shared__ float s_acc[2][HEADS * DIM];   // 2 x 256
    __shared__ float s_part[256];
    s_acc[0][h * 64 + j] = Hr.x;
    s_acc[1][h * 64 + j] = Hr.y;
    __syncthreads();

    {   // thread t: row r = t>>7, k-half hf = (t>>6)&1, col jj = t&63
        int r = t >> 7, hf = (t >> 6) & 1, jj = t & 63;
        const float* Wp = W_dense + (hf * 128) * DIM + jj;
        const float* ap = &s_acc[r][hf * 128];
        float part = 0.f;
        #pragma unroll 8
        for (int k = 0; k < 128; ++k)
            part = fmaf(ap[k], Wp[k * DIM], part);   // ap broadcast, Wp coalesced
        s_part[t] = part;
    }
    __syncthreads();
    if (t < 128) {
        int r = t >> 6, jj = t & 63;
        y[(n0 + r * 64) * DIM + jj] =
            b_dense[jj] + s_part[r * 128 + jj] + s_part[r * 128 + 64 + jj];
    }
}

extern "C" void kernel_launch(void* const* d_in, const int* in_sizes, int n_in,
                              void* d_out, int out_size, void* d_ws, size_t ws_size,
                              hipStream_t stream) {
    const float* queries = (const float*)d_in[0];
    const float* values  = (const float*)d_in[1];
    const float* U_re    = (const float*)d_in[2];
    const float* U_im    = (const float*)d_in[3];
    const float* bias    = (const float*)d_in[4];
    const float* theta1  = (const float*)d_in[5];
    const float* phi1    = (const float*)d_in[6];
    const float* theta2  = (const float*)d_in[7];
    const float* phi2    = (const float*)d_in[8];
    const float* omega   = (const float*)d_in[9];
    const float* W_dense = (const float*)d_in[10];
    const float* b_dense = (const float*)d_in[11];
    float* y = (float*)d_out;

    f2* Av = (f2*)d_ws;   // HEADS*1024*64 f2 = 2 MB (+2 KB over-read slack)

    k_av<<<256, 256, 0, stream>>>(values, U_re, U_im, Av);
    k_rnn_dense<<<512, 256, 0, stream>>>(queries, U_re, U_im, bias, theta1,
                                         phi1, theta2, phi2, omega, Av,
                                         W_dense, b_dense, y);
}

// Round 9
// 117.343 us; speedup vs baseline: 1.1203x; 1.0183x over previous
//
#include <hip/hip_runtime.h>
#include <math.h>

#define DIM 64
#define HEADS 4
#define BB 8
#define QQ 128
#define VV 128
#define NN (BB*QQ)   // 1024

typedef float f2 __attribute__((ext_vector_type(2)));

// DPP quad_perm(1,0,3,2): swap adjacent lanes (xor 1). VALU, no DS.
__device__ __forceinline__ float dpp_swap1(float x) {
    return __int_as_float(__builtin_amdgcn_update_dpp(
        0, __float_as_int(x), 0xB1, 0xF, 0xF, true));
}
// wave_shr:1 — lane j gets lane j-1 (lane 0 -> 0 via bound_ctrl). VALU, no DS.
__device__ __forceinline__ float dpp_wshr1(float x) {
    return __int_as_float(__builtin_amdgcn_update_dpp(
        0, __float_as_int(x), 0x138, 0xF, 0xF, true));
}
// wave_shl:1 — lane j gets lane j+1 (lane 63 -> 0 via bound_ctrl). VALU, no DS.
__device__ __forceinline__ float dpp_wshl1(float x) {
    return __int_as_float(__builtin_amdgcn_update_dpp(
        0, __float_as_int(x), 0x130, 0xF, 0xF, true));
}
__device__ __forceinline__ f2 dpp2_swap1(f2 x) {
    f2 r; r.x = dpp_swap1(x.x); r.y = dpp_swap1(x.y); return r;
}
__device__ __forceinline__ f2 dpp2_shl1(f2 x) {
    f2 r; r.x = dpp_wshl1(x.x); r.y = dpp_wshl1(x.y); return r;
}
__device__ __forceinline__ f2 dpp2_shr1(f2 x) {
    f2 r; r.x = dpp_wshr1(x.x); r.y = dpp_wshr1(x.y); return r;
}

// K1: Av[h][row][j] = (re,im) of sum_i values[row,i] * U[h, 64+i, j]
__global__ __launch_bounds__(256) void k_av(const float* __restrict__ values,
                                            const float* __restrict__ U_re,
                                            const float* __restrict__ U_im,
                                            f2* __restrict__ Av) {
    int tid = blockIdx.x * blockDim.x + threadIdx.x;
    int w = tid >> 6;            // 0..1023
    int j = tid & 63;
    int h = w >> 8;              // 0..3
    int r0 = (w & 255) << 2;     // first of 4 rows within head h (0..1020)
    const float* vrow = values + r0 * DIM;                     // wave-uniform
    const float* ur = U_re + (h * 2 * DIM + DIM) * DIM + j;    // bottom half
    const float* ui = U_im + (h * 2 * DIM + DIM) * DIM + j;
    f2 a0 = 0.f, a1 = 0.f, a2 = 0.f, a3 = 0.f;
    #pragma unroll 8
    for (int i = 0; i < DIM; ++i) {
        f2 u; u.x = ur[i * DIM]; u.y = ui[i * DIM];
        a0 += vrow[i] * u;                 // s_load scalars broadcast
        a1 += vrow[DIM + i] * u;
        a2 += vrow[2 * DIM + i] * u;
        a3 += vrow[3 * DIM + i] * u;
    }
    f2* out = Av + (h * 1024 + r0) * DIM + j;
    out[0] = a0; out[DIM] = a1; out[2 * DIM] = a2; out[3 * DIM] = a3;
}

// K2: block = (b, q): 4 waves = 4 heads; each wave scans TWO rows (q, q+64),
// states packed as f2 (component = row). No DS / branches in the scan.
// Av consumed in batches of 8 with register double-buffering: the 8-step
// compute phase has no outstanding-memory dependency.
// Algebra: layer1 = real Givens + phase on even lanes; layer2 = real 3-tap
// + single fused phase (e2-odd * e^{i*omega}). 18 fma/row-step.
__global__ __launch_bounds__(256) void k_rnn_dense(
        const float* __restrict__ queries,
        const float* __restrict__ U_re,
        const float* __restrict__ U_im,
        const float* __restrict__ bias,
        const float* __restrict__ theta1,
        const float* __restrict__ phi1,
        const float* __restrict__ theta2,
        const float* __restrict__ phi2,
        const float* __restrict__ omega,
        const f2* __restrict__ Av,
        const float* __restrict__ W_dense,
        const float* __restrict__ b_dense,
        float* __restrict__ y) {
    int b = blockIdx.x >> 6;   // 0..7
    int q = blockIdx.x & 63;   // 0..63
    int t = threadIdx.x;
    int h = t >> 6;            // head = wave
    int j = t & 63;            // state dim = lane
    int n0 = b * 128 + q;      // row A (block-uniform)
    int n1 = n0 + 64;          // row B

    // ---- layer 1: t = E1 .* (C1*h + S1*swap1(h)), real C1,S1 ----
    int k1 = j >> 1;
    float th1 = theta1[h * 32 + k1], ph1 = phi1[h * 32 + k1];
    float C1 = cosf(th1);
    float s1v = sinf(th1);
    float S1, E1r, E1i;
    if ((j & 1) == 0) {        // even = 'a': e1*(c1*self - s1*partner)
        S1 = -s1v; E1r = cosf(ph1); E1i = sinf(ph1);
    } else {                   // odd = 'b': s1*partner + c1*self (no phase)
        S1 = s1v; E1r = 1.f; E1i = 0.f;
    }

    // ---- layer 2: s = PH .* (C2*t + SL*shl1(t) + SR*shr1(t)), real C2,SL,SR;
    //      PH = (odd interior ? e2 : 1) * e^{i*omega}  ----
    float C2, SL, SR, p2r, p2i;
    if (j == 0 || j == 63) {
        C2 = 1.f; SL = 0.f; SR = 0.f; p2r = 1.f; p2i = 0.f;
    } else {
        int k2 = (j - 1) >> 1;
        float th2 = theta2[h * 31 + k2], ph2 = phi2[h * 31 + k2];
        float c2 = cosf(th2), s2 = sinf(th2);
        if (j & 1) {           // odd = 'a': e2*(c2*self - s2*next)
            C2 = c2; SL = -s2; SR = 0.f;
            p2r = cosf(ph2); p2i = sinf(ph2);
        } else {               // even = 'b': s2*prev + c2*self
            C2 = c2; SR = s2; SL = 0.f;
            p2r = 1.f; p2i = 0.f;
        }
    }
    float om = omega[h * 64 + j];
    float eor = cosf(om), eoi = sinf(om);
    float PHr = p2r * eor - p2i * eoi;
    float PHi = p2r * eoi + p2i * eor;

    float bj = bias[h * 64 + j];

    // ---- Aq for both rows (packed); query rows block-uniform -> s_load ----
    const float* qrow0 = queries + n0 * DIM;
    const float* qrow1 = queries + n1 * DIM;
    const float* ur = U_re + (h * 2 * DIM) * DIM + j;
    const float* ui = U_im + (h * 2 * DIM) * DIM + j;
    f2 Uqr = 0.f, Uqi = 0.f;   // component 0 = row n0, 1 = row n1
    #pragma unroll 8
    for (int i = 0; i < DIM; ++i) {
        f2 a; a.x = qrow0[i]; a.y = qrow1[i];
        float wr = ur[i * DIM], wi = ui[i * DIM];
        Uqr += a * wr;
        Uqi += a * wi;
    }

    const f2* p = Av + (h * 1024 + b * 128) * DIM + j;

    // ---- scan: batches of 8 with register double-buffering ----
    f2 buf[8], nxt[8];
    #pragma unroll
    for (int k = 0; k < 8; ++k) buf[k] = p[k * DIM];

    f2 Hr = 0.f, Hi = 0.f;
    for (int vb = 0; vb < VV; vb += 8) {
        // prefetch next batch (last batch: harmlessly re-read current)
        const f2* pn = p + ((vb < VV - 8) ? 8 * DIM : 0);
        #pragma unroll
        for (int k = 0; k < 8; ++k) nxt[k] = pn[k * DIM];
        p = pn;
        #pragma unroll
        for (int k = 0; k < 8; ++k) {
            f2 av = buf[k];
            f2 uvr = Uqr + av.x;           // off-chain input term
            f2 uvi = Uqi + av.y;
            // layer 1: real Givens + phase (even lanes)
            f2 Pr = dpp2_swap1(Hr), Pi = dpp2_swap1(Hi);
            f2 tpr = C1 * Hr + S1 * Pr;
            f2 tpi = C1 * Hi + S1 * Pi;
            f2 Tr = E1r * tpr - E1i * tpi;
            f2 Ti = E1r * tpi + E1i * tpr;
            // layer 2: real 3-tap + fused phase
            f2 Lr = dpp2_shl1(Tr), Li = dpp2_shl1(Ti);
            f2 Rr = dpp2_shr1(Tr), Ri = dpp2_shr1(Ti);
            f2 spr = C2 * Tr + SL * Lr + SR * Rr;
            f2 spi = C2 * Ti + SL * Li + SR * Ri;
            f2 Zr = (PHr * spr - PHi * spi) + uvr;
            f2 Zi = (PHr * spi + PHi * spr) + uvi;
            // modrelu: sc = max(1 + b/m, 0), 1/m = rsq(|z|^2 + eps)
            f2 q2 = Zr * Zr + Zi * Zi + 1e-10f;
            float rsx = __builtin_amdgcn_rsqf(q2.x);
            float rsy = __builtin_amdgcn_rsqf(q2.y);
            f2 sc;
            sc.x = fmaxf(fmaf(bj, rsx, 1.f), 0.f);
            sc.y = fmaxf(fmaf(bj, rsy, 1.f), 0.f);
            Hr = Zr * sc; Hi = Zi * sc;
        }
        #pragma unroll
        for (int k = 0; k < 8; ++k) buf[k] = nxt[k];
    }

    // ---- fused dense for rows n0, n1 ----
    __shared__ float s_acc[2][HEADS * DIM];   // 2 x 256
    __shared__ float s_part[256];
    s_acc[0][h * 64 + j] = Hr.x;
    s_acc[1][h * 64 + j] = Hr.y;
    __syncthreads();

    {   // thread t: row r = t>>7, k-half hf = (t>>6)&1, col jj = t&63
        int r = t >> 7, hf = (t >> 6) & 1, jj = t & 63;
        const float* Wp = W_dense + (hf * 128) * DIM + jj;
        const float* ap = &s_acc[r][hf * 128];
        float part = 0.f;
        #pragma unroll 8
        for (int k = 0; k < 128; ++k)
            part = fmaf(ap[k], Wp[k * DIM], part);   // ap broadcast, Wp coalesced
        s_part[t] = part;
    }
    __syncthreads();
    if (t < 128) {
        int r = t >> 6, jj = t & 63;
        y[(n0 + r * 64) * DIM + jj] =
            b_dense[jj] + s_part[r * 128 + jj] + s_part[r * 128 + 64 + jj];
    }
}

extern "C" void kernel_launch(void* const* d_in, const int* in_sizes, int n_in,
                              void* d_out, int out_size, void* d_ws, size_t ws_size,
                              hipStream_t stream) {
    const float* queries = (const float*)d_in[0];
    const float* values  = (const float*)d_in[1];
    const float* U_re    = (const float*)d_in[2];
    const float* U_im    = (const float*)d_in[3];
    const float* bias    = (const float*)d_in[4];
    const float* theta1  = (const float*)d_in[5];
    const float* phi1    = (const float*)d_in[6];
    const float* theta2  = (const float*)d_in[7];
    const float* phi2    = (const float*)d_in[8];
    const float* omega   = (const float*)d_in[9];
    const float* W_dense = (const float*)d_in[10];
    const float* b_dense = (const float*)d_in[11];
    float* y = (float*)d_out;

    f2* Av = (f2*)d_ws;   // HEADS*1024*64 f2 = 2 MB

    k_av<<<256, 256, 0, stream>>>(values, U_re, U_im, Av);
    k_rnn_dense<<<512, 256, 0, stream>>>(queries, U_re, U_im, bias, theta1,
                                         phi1, theta2, phi2, omega, Av,
                                         W_dense, b_dense, y);
}

// Round 10
// 116.281 us; speedup vs baseline: 1.1305x; 1.0091x over previous
//
#include <hip/hip_runtime.h>
#include <math.h>

#define DIM 64
#define HEADS 4
#define BB 8
#define QQ 128
#define VV 128
#define NN (BB*QQ)   // 1024

typedef float f2 __attribute__((ext_vector_type(2)));

// DPP quad_perm(1,0,3,2): swap adjacent lanes (xor 1). VALU, no DS.
__device__ __forceinline__ float dpp_swap1(float x) {
    return __int_as_float(__builtin_amdgcn_update_dpp(
        0, __float_as_int(x), 0xB1, 0xF, 0xF, true));
}
// wave_shr:1 — lane j gets lane j-1 (lane 0 -> 0 via bound_ctrl). VALU, no DS.
__device__ __forceinline__ float dpp_wshr1(float x) {
    return __int_as_float(__builtin_amdgcn_update_dpp(
        0, __float_as_int(x), 0x138, 0xF, 0xF, true));
}
// wave_shl:1 — lane j gets lane j+1 (lane 63 -> 0 via bound_ctrl). VALU, no DS.
__device__ __forceinline__ float dpp_wshl1(float x) {
    return __int_as_float(__builtin_amdgcn_update_dpp(
        0, __float_as_int(x), 0x130, 0xF, 0xF, true));
}
__device__ __forceinline__ f2 dpp2_swap1(f2 x) {
    f2 r; r.x = dpp_swap1(x.x); r.y = dpp_swap1(x.y); return r;
}
__device__ __forceinline__ f2 dpp2_shl1(f2 x) {
    f2 r; r.x = dpp_wshl1(x.x); r.y = dpp_wshl1(x.y); return r;
}
__device__ __forceinline__ f2 dpp2_shr1(f2 x) {
    f2 r; r.x = dpp_wshr1(x.x); r.y = dpp_wshr1(x.y); return r;
}

// Manual global load, 8B, immediate byte offset. Volatile: cannot be sunk,
// CSE'd, or reordered against other volatile asm (the waitcnt below).
#define GLOAD(dst, ptr, OFFSTR) \
    asm volatile("global_load_dwordx2 %0, %1, off offset:" OFFSTR \
                 : "=v"(dst) : "v"(ptr))

// K1: Av[h][row][j] = (re,im) of sum_i values[row,i] * U[h, 64+i, j]
// 2 rows per wave; 512 blocks -> 2 waves/SIMD.
__global__ __launch_bounds__(256) void k_av(const float* __restrict__ values,
                                            const float* __restrict__ U_re,
                                            const float* __restrict__ U_im,
                                            f2* __restrict__ Av) {
    int tid = blockIdx.x * blockDim.x + threadIdx.x;
    int w = tid >> 6;            // 0..2047
    int j = tid & 63;
    int h = w >> 9;              // 0..3
    int r0 = (w & 511) << 1;     // first of 2 rows within head h (0..1022)
    const float* vrow = values + r0 * DIM;                     // wave-uniform
    const float* ur = U_re + (h * 2 * DIM + DIM) * DIM + j;    // bottom half
    const float* ui = U_im + (h * 2 * DIM + DIM) * DIM + j;
    f2 a0 = 0.f, a1 = 0.f;
    #pragma unroll 8
    for (int i = 0; i < DIM; ++i) {
        f2 u; u.x = ur[i * DIM]; u.y = ui[i * DIM];
        a0 += vrow[i] * u;                 // s_load scalars broadcast
        a1 += vrow[DIM + i] * u;
    }
    f2* out = Av + (h * 1024 + r0) * DIM + j;
    out[0] = a0; out[DIM] = a1;
}

// K2: block = (b, q): 4 waves = 4 heads; each wave scans TWO rows (q, q+64),
// states packed as f2 (component = row). No DS / branches in the scan.
// Av consumed in batches of 8 with an inline-asm register pipeline: 8
// global_load_dwordx2 issued per batch, ONE s_waitcnt vmcnt(0) per batch,
// placed AFTER the 8-step compute so load latency is fully overlapped.
__global__ __launch_bounds__(256) void k_rnn_dense(
        const float* __restrict__ queries,
        const float* __restrict__ U_re,
        const float* __restrict__ U_im,
        const float* __restrict__ bias,
        const float* __restrict__ theta1,
        const float* __restrict__ phi1,
        const float* __restrict__ theta2,
        const float* __restrict__ phi2,
        const float* __restrict__ omega,
        const f2* __restrict__ Av,
        const float* __restrict__ W_dense,
        const float* __restrict__ b_dense,
        float* __restrict__ y) {
    int b = blockIdx.x >> 6;   // 0..7
    int q = blockIdx.x & 63;   // 0..63
    int t = threadIdx.x;
    int h = t >> 6;            // head = wave
    int j = t & 63;            // state dim = lane
    int n0 = b * 128 + q;      // row A (block-uniform)
    int n1 = n0 + 64;          // row B

    // ---- layer 1: t = E1 .* (C1*h + S1*swap1(h)), real C1,S1 ----
    int k1 = j >> 1;
    float th1 = theta1[h * 32 + k1], ph1 = phi1[h * 32 + k1];
    float C1 = cosf(th1);
    float s1v = sinf(th1);
    float S1, E1r, E1i;
    if ((j & 1) == 0) {        // even = 'a': e1*(c1*self - s1*partner)
        S1 = -s1v; E1r = cosf(ph1); E1i = sinf(ph1);
    } else {                   // odd = 'b': s1*partner + c1*self (no phase)
        S1 = s1v; E1r = 1.f; E1i = 0.f;
    }

    // ---- layer 2: s = PH .* (C2*t + SL*shl1(t) + SR*shr1(t)) ----
    float C2, SL, SR, p2r, p2i;
    if (j == 0 || j == 63) {
        C2 = 1.f; SL = 0.f; SR = 0.f; p2r = 1.f; p2i = 0.f;
    } else {
        int k2 = (j - 1) >> 1;
        float th2 = theta2[h * 31 + k2], ph2 = phi2[h * 31 + k2];
        float c2 = cosf(th2), s2 = sinf(th2);
        if (j & 1) {           // odd = 'a': e2*(c2*self - s2*next)
            C2 = c2; SL = -s2; SR = 0.f;
            p2r = cosf(ph2); p2i = sinf(ph2);
        } else {               // even = 'b': s2*prev + c2*self
            C2 = c2; SR = s2; SL = 0.f;
            p2r = 1.f; p2i = 0.f;
        }
    }
    float om = omega[h * 64 + j];
    float eor = cosf(om), eoi = sinf(om);
    float PHr = p2r * eor - p2i * eoi;
    float PHi = p2r * eoi + p2i * eor;

    float bj = bias[h * 64 + j];

    // ---- Aq for both rows (packed); query rows block-uniform -> s_load ----
    const float* qrow0 = queries + n0 * DIM;
    const float* qrow1 = queries + n1 * DIM;
    const float* ur = U_re + (h * 2 * DIM) * DIM + j;
    const float* ui = U_im + (h * 2 * DIM) * DIM + j;
    f2 Uqr = 0.f, Uqi = 0.f;   // component 0 = row n0, 1 = row n1
    #pragma unroll 8
    for (int i = 0; i < DIM; ++i) {
        f2 a; a.x = qrow0[i]; a.y = qrow1[i];
        float wr = ur[i * DIM], wi = ui[i * DIM];
        Uqr += a * wr;
        Uqi += a * wi;
    }

    // one scan step (serial chain on Hr/Hi)
    f2 Hr = 0.f, Hi = 0.f;
    auto step = [&](f2 av) {
        f2 uvr = Uqr + av.x;               // off-chain input term
        f2 uvi = Uqi + av.y;
        // layer 1: real Givens + phase (even lanes)
        f2 Pr = dpp2_swap1(Hr), Pi = dpp2_swap1(Hi);
        f2 tpr = C1 * Hr + S1 * Pr;
        f2 tpi = C1 * Hi + S1 * Pi;
        f2 Tr = E1r * tpr - E1i * tpi;
        f2 Ti = E1r * tpi + E1i * tpr;
        // layer 2: real 3-tap + fused phase
        f2 Lr = dpp2_shl1(Tr), Li = dpp2_shl1(Ti);
        f2 Rr = dpp2_shr1(Tr), Ri = dpp2_shr1(Ti);
        f2 spr = C2 * Tr + SL * Lr + SR * Rr;
        f2 spi = C2 * Ti + SL * Li + SR * Ri;
        f2 Zr = (PHr * spr - PHi * spi) + uvr;
        f2 Zi = (PHr * spi + PHi * spr) + uvi;
        // modrelu: sc = max(1 + b/m, 0), 1/m = rsq(|z|^2 + eps)
        f2 q2 = Zr * Zr + Zi * Zi + 1e-10f;
        float rsx = __builtin_amdgcn_rsqf(q2.x);
        float rsy = __builtin_amdgcn_rsqf(q2.y);
        f2 sc;
        sc.x = fmaxf(fmaf(bj, rsx, 1.f), 0.f);
        sc.y = fmaxf(fmaf(bj, rsy, 1.f), 0.f);
        Hr = Zr * sc; Hi = Zi * sc;
    };

    const f2* pcur = Av + (h * 1024 + b * 128) * DIM + j;

    // prologue: load batch 0 into c0..c7
    f2 c0, c1, c2v, c3, c4, c5, c6, c7;
    GLOAD(c0, pcur, "0");    GLOAD(c1, pcur, "512");
    GLOAD(c2v, pcur, "1024"); GLOAD(c3, pcur, "1536");
    GLOAD(c4, pcur, "2048"); GLOAD(c5, pcur, "2560");
    GLOAD(c6, pcur, "3072"); GLOAD(c7, pcur, "3584");
    asm volatile("s_waitcnt vmcnt(0)"
                 : "+v"(c0), "+v"(c1), "+v"(c2v), "+v"(c3),
                   "+v"(c4), "+v"(c5), "+v"(c6), "+v"(c7));

    for (int vb = 0; vb < VV; vb += 8) {
        // issue next batch's loads (last batch: re-read current — discarded)
        const f2* pn = (vb < VV - 8) ? (pcur + 8 * DIM) : pcur;
        f2 x0, x1, x2, x3, x4, x5, x6, x7;
        GLOAD(x0, pn, "0");    GLOAD(x1, pn, "512");
        GLOAD(x2, pn, "1024"); GLOAD(x3, pn, "1536");
        GLOAD(x4, pn, "2048"); GLOAD(x5, pn, "2560");
        GLOAD(x6, pn, "3072"); GLOAD(x7, pn, "3584");
        // compute current batch — no memory dependency
        step(c0); step(c1); step(c2v); step(c3);
        step(c4); step(c5); step(c6); step(c7);
        // drain the in-flight loads, then rotate
        asm volatile("s_waitcnt vmcnt(0)"
                     : "+v"(x0), "+v"(x1), "+v"(x2), "+v"(x3),
                       "+v"(x4), "+v"(x5), "+v"(x6), "+v"(x7));
        c0 = x0; c1 = x1; c2v = x2; c3 = x3;
        c4 = x4; c5 = x5; c6 = x6; c7 = x7;
        pcur = pn;
    }

    // ---- fused dense for rows n0, n1 ----
    __shared__ float s_acc[2][HEADS * DIM];   // 2 x 256
    __shared__ float s_part[256];
    s_acc[0][h * 64 + j] = Hr.x;
    s_acc[1][h * 64 + j] = Hr.y;
    __syncthreads();

    {   // thread t: row r = t>>7, k-half hf = (t>>6)&1, col jj = t&63
        int r = t >> 7, hf = (t >> 6) & 1, jj = t & 63;
        const float* Wp = W_dense + (hf * 128) * DIM + jj;
        const float* ap = &s_acc[r][hf * 128];
        float part = 0.f;
        #pragma unroll 8
        for (int k = 0; k < 128; ++k)
            part = fmaf(ap[k], Wp[k * DIM], part);   // ap broadcast, Wp coalesced
        s_part[t] = part;
    }
    __syncthreads();
    if (t < 128) {
        int r = t >> 6, jj = t & 63;
        y[(n0 + r * 64) * DIM + jj] =
            b_dense[jj] + s_part[r * 128 + jj] + s_part[r * 128 + 64 + jj];
    }
}

extern "C" void kernel_launch(void* const* d_in, const int* in_sizes, int n_in,
                              void* d_out, int out_size, void* d_ws, size_t ws_size,
                              hipStream_t stream) {
    const float* queries = (const float*)d_in[0];
    const float* values  = (const float*)d_in[1];
    const float* U_re    = (const float*)d_in[2];
    const float* U_im    = (const float*)d_in[3];
    const float* bias    = (const float*)d_in[4];
    const float* theta1  = (const float*)d_in[5];
    const float* phi1    = (const float*)d_in[6];
    const float* theta2  = (const float*)d_in[7];
    const float* phi2    = (const float*)d_in[8];
    const float* omega   = (const float*)d_in[9];
    const float* W_dense = (const float*)d_in[10];
    const float* b_dense = (const float*)d_in[11];
    float* y = (float*)d_out;

    f2* Av = (f2*)d_ws;   // HEADS*1024*64 f2 = 2 MB

    k_av<<<512, 256, 0, stream>>>(values, U_re, U_im, Av);
    k_rnn_dense<<<512, 256, 0, stream>>>(queries, U_re, U_im, bias, theta1,
                                         phi1, theta2, phi2, omega, Av,
                                         W_dense, b_dense, y);
}